// Round 1
// baseline (118.205 us; speedup 1.0000x reference)
//
#include <hip/hip_runtime.h>
#include <math.h>

// Problem constants: B=32, T=1024, D_IN=64, H=128, NH=4, HD=32, R=3
#define TT 1024

// ---------------------------------------------------------------------------
// Fully fused kernel: one block per batch b (32 blocks x 1024 threads).
// All intermediates in LDS; zero workspace; zero inter-kernel boundaries.
// Phases (separated by __syncthreads):
//   A: r[4][64]   (= old k_qr, verbatim thread mapping on tid<256/512)
//   B: t[n][j] = x[b,j,:].r[n,:]        (= old k_t, 64 row-groups/iter)
//   C: smooth+softmax+Adj^T smooth      (= old k_sm, per-head 256-thr groups)
//   D: u[n][d] = sum_j p~[n][j] x[j,d]  (= old k_u+chunk-reduce, same nesting)
//   E: tail mat-vecs + LN + gelu + out  (= old k_tail, verbatim on tid<128)
// ---------------------------------------------------------------------------
__global__ __launch_bounds__(1024) void k_fused(
    const float* __restrict__ x, const float* __restrict__ theta_w,
    const float* __restrict__ theta_b, const float* __restrict__ ipw,
    const float* __restrict__ ipb, const float* __restrict__ Wout,
    const float* __restrict__ outb, const float* __restrict__ ln_g,
    const float* __restrict__ ln_b, const float* __restrict__ w1,
    const float* __restrict__ b1, const float* __restrict__ w2,
    const float* __restrict__ b2, float* __restrict__ out) {
  const int b = blockIdx.x;
  const int tid = threadIdx.x;

  __shared__ float s_xs[64];
  __shared__ float s_y[128];
  __shared__ float s_q[128];
  __shared__ float s_z[4][128];
  __shared__ __align__(16) float s_r[256];     // r[n*64+d]
  __shared__ __align__(16) float s_t[4][TT];   // raw scores per head
  __shared__ __align__(16) float s_p[4][TT];   // exp(...)/wsum per head
  __shared__ __align__(16) float s_ptT[TT][4]; // p~ transposed: [j][n]
  __shared__ float s_up[16][4][64];            // per-chunk u partials
  __shared__ float s_u[256];                   // u[n*64+d]
  __shared__ float s_w[4][128];
  __shared__ float s_o[128], s_ln[128], s_hid[128];
  __shared__ float s_red4[4][4];
  __shared__ float s_red2[2];

  const float* __restrict__ xb = x + (size_t)b * TT * 64;

  // ---------------- A: r[n][d] ----------------
  if (tid < 64) {
    float acc = xb[(TT - 1) * 64 + tid]
              + 0.5f        * xb[(TT - 2) * 64 + tid]
              + (1.f / 3.f) * xb[(TT - 3) * 64 + tid]
              + 0.25f       * xb[(TT - 4) * 64 + tid];
    s_xs[tid] = acc * (12.f / 25.f);
  }
  __syncthreads();
  if (tid < 128) {  // y = theta*xs + theta_b
    const float* tr = theta_w + tid * 64;
    float acc = theta_b[tid];
    for (int d = 0; d < 64; ++d) acc += tr[d] * s_xs[d];
    s_y[tid] = acc;
  }
  __syncthreads();
  if (tid < 256) {  // q_e = Wq[e,:].y + ipb[e]
    const int g = tid >> 4, l = tid & 15;
    for (int pass = 0; pass < 8; ++pass) {
      const int e = pass * 16 + g;
      const float* wr = ipw + e * 128 + l * 8;
      float acc = 0.f;
      #pragma unroll
      for (int u = 0; u < 8; ++u) acc += wr[u] * s_y[l * 8 + u];
      acc += __shfl_xor(acc, 1);
      acc += __shfl_xor(acc, 2);
      acc += __shfl_xor(acc, 4);
      acc += __shfl_xor(acc, 8);
      if (l == 0) s_q[e] = acc + ipb[e];
    }
  }
  __syncthreads();
  if (tid < 512) {  // z[n][c] = sum_e Wk[128+n*32+e, c] * q[n*32+e]
    const int n = tid >> 7, c = tid & 127;
    const float* qn = &s_q[n * 32];
    float acc = 0.f;
    for (int e = 0; e < 32; ++e) acc += ipw[(128 + n * 32 + e) * 128 + c] * qn[e];
    s_z[n][c] = acc;
  }
  __syncthreads();
  if (tid < 256) {  // r[n][d] = sum_c theta[c,d] z[n][c], fold 1/sqrt(32)
    const int n = tid >> 6, d = tid & 63;
    const float* zn = s_z[n];
    float acc = 0.f;
    for (int c = 0; c < 128; ++c) acc += theta_w[c * 64 + d] * zn[c];
    s_r[n * 64 + d] = acc * 0.17677669529663687f;
  }
  __syncthreads();

  // ---------------- B: t[n][j] = x[b,j,:].r[n,:] ----------------
  {
    const int g = tid >> 4, l = tid & 15;  // 64 row-groups x 16 lanes
    const float4 r0 = ((const float4*)(s_r +   0))[l];
    const float4 r1 = ((const float4*)(s_r +  64))[l];
    const float4 r2 = ((const float4*)(s_r + 128))[l];
    const float4 r3 = ((const float4*)(s_r + 192))[l];
    for (int it = 0; it < 16; ++it) {
      const int j = it * 64 + g;
      const float4 xv = ((const float4*)(xb + j * 64))[l];
      float p0 = xv.x * r0.x + xv.y * r0.y + xv.z * r0.z + xv.w * r0.w;
      float p1 = xv.x * r1.x + xv.y * r1.y + xv.z * r1.z + xv.w * r1.w;
      float p2 = xv.x * r2.x + xv.y * r2.y + xv.z * r2.z + xv.w * r2.w;
      float p3 = xv.x * r3.x + xv.y * r3.y + xv.z * r3.z + xv.w * r3.w;
      #pragma unroll
      for (int m = 1; m <= 8; m <<= 1) {
        p0 += __shfl_xor(p0, m);
        p1 += __shfl_xor(p1, m);
        p2 += __shfl_xor(p2, m);
        p3 += __shfl_xor(p3, m);
      }
      if (l == 0) {
        s_t[0][j] = p0;
        s_t[1][j] = p1;
        s_t[2][j] = p2;
        s_t[3][j] = p3;
      }
    }
  }
  __syncthreads();

  // ---------------- C: smooth, softmax, Adj^T smooth ----------------
  // head hg handled by 256-thread group; thread covers j = ht + k*256
  // (stride-256 mapping -> conflict-free LDS tap reads)
  {
    const int hg = tid >> 8, ht = tid & 255;
    float sc[4], wsv[4];
    float lmax = -1e30f;
    #pragma unroll
    for (int k = 0; k < 4; ++k) {
      const int s = ht + k * 256;
      float acc = 0.f, wsum = 0.f;
      #pragma unroll
      for (int dj = -3; dj <= 3; ++dj) {
        const int j = s + dj;
        if (j >= 0 && j < TT) {
          const float w = 1.f / (1.f + (float)(dj < 0 ? -dj : dj));
          acc += w * s_t[hg][j];
          wsum += w;
        }
      }
      sc[k] = acc / wsum;
      wsv[k] = wsum;
      lmax = fmaxf(lmax, sc[k]);
    }
    #pragma unroll
    for (int m = 32; m >= 1; m >>= 1) lmax = fmaxf(lmax, __shfl_xor(lmax, m));
    if ((ht & 63) == 0) s_red4[hg][ht >> 6] = lmax;
    __syncthreads();
    const float bmax = fmaxf(fmaxf(s_red4[hg][0], s_red4[hg][1]),
                             fmaxf(s_red4[hg][2], s_red4[hg][3]));
    __syncthreads();
    float lsum = 0.f;
    #pragma unroll
    for (int k = 0; k < 4; ++k) {
      const float e = expf(sc[k] - bmax);
      lsum += e;
      s_p[hg][ht + k * 256] = e / wsv[k];  // pre-divide by rowsum
    }
    #pragma unroll
    for (int m = 32; m >= 1; m >>= 1) lsum += __shfl_xor(lsum, m);
    if ((ht & 63) == 0) s_red4[hg][ht >> 6] = lsum;
    __syncthreads();
    const float inv_denom =
        1.f / (s_red4[hg][0] + s_red4[hg][1] + s_red4[hg][2] + s_red4[hg][3]);
    #pragma unroll
    for (int k = 0; k < 4; ++k) {
      const int j = ht + k * 256;
      float acc = 0.f;
      #pragma unroll
      for (int dj = -3; dj <= 3; ++dj) {
        const int s = j + dj;
        if (s >= 0 && s < TT)
          acc += (1.f / (1.f + (float)(dj < 0 ? -dj : dj))) * s_p[hg][s];
      }
      s_ptT[j][hg] = acc * inv_denom;
    }
  }
  __syncthreads();

  // ---------------- D: u[n][d] = sum_j p~[n][j] x[j][d] ----------------
  // thread (jp, d): own chunk jp of 64 j's, all 4 heads in registers.
  {
    const int jp = tid >> 6, d = tid & 63;
    const float* xr = xb + (size_t)(jp * 64) * 64 + d;
    float a0 = 0.f, a1 = 0.f, a2 = 0.f, a3 = 0.f;
    for (int jj = 0; jj < 64; ++jj) {
      const float xv = xr[jj * 64];
      const int j = jp * 64 + jj;
      const float4 pv = *(const float4*)(&s_ptT[j][0]);
      a0 += pv.x * xv;
      a1 += pv.y * xv;
      a2 += pv.z * xv;
      a3 += pv.w * xv;
    }
    s_up[jp][0][d] = a0;
    s_up[jp][1][d] = a1;
    s_up[jp][2][d] = a2;
    s_up[jp][3][d] = a3;
  }
  __syncthreads();
  if (tid < 256) {  // chunk reduce, ascending c (matches old k_tail order)
    const int n = tid >> 6, d = tid & 63;
    float acc = 0.f;
    for (int c = 0; c < 16; ++c) acc += s_up[c][n][d];
    s_u[n * 64 + d] = acc;
  }
  __syncthreads();

  // ---------------- E: tail ----------------
  if (tid < 512) {  // w[n][c] = theta[c,:].u(n) + theta_b[c]
    const int n = tid >> 7, c = tid & 127;
    const float* tr = theta_w + c * 64;
    const float* un = &s_u[n * 64];
    float acc = theta_b[c];
    for (int d = 0; d < 64; ++d) acc += tr[d] * un[d];
    s_w[n][c] = acc;
  }
  __syncthreads();
  if (tid < 128) {  // o_e = Wv[256+e,:].w(n(e)) + ipb[256+e]
    const int e = tid, n = e >> 5;
    const float* wr = ipw + (256 + e) * 128;
    const float* wn = s_w[n];
    float acc = ipb[256 + e];
    for (int c = 0; c < 128; ++c) acc += wr[c] * wn[c];
    s_o[e] = acc;
  }
  __syncthreads();
  float a_val = 0.f;
  if (tid < 128) {
    const int e = tid;
    a_val = outb[e];
    const float* wr = Wout + e * 128;
    for (int f = 0; f < 128; ++f) a_val += wr[f] * s_o[f];
    float sum = a_val;
    #pragma unroll
    for (int m = 32; m >= 1; m >>= 1) sum += __shfl_xor(sum, m);
    if ((e & 63) == 0) s_red2[e >> 6] = sum;
  }
  __syncthreads();
  const float mu = (s_red2[0] + s_red2[1]) * (1.f / 128.f);
  __syncthreads();
  if (tid < 128) {
    const float d = a_val - mu;
    float sq = d * d;
    #pragma unroll
    for (int m = 32; m >= 1; m >>= 1) sq += __shfl_xor(sq, m);
    if ((tid & 63) == 0) s_red2[tid >> 6] = sq;
  }
  __syncthreads();
  if (tid < 128) {
    const int e = tid;
    const float var = (s_red2[0] + s_red2[1]) * (1.f / 128.f);
    const float d = a_val - mu;
    const float ln = d / sqrtf(var + 1e-5f) * ln_g[e] + ln_b[e];
    s_ln[e] = ln;
  }
  __syncthreads();
  if (tid < 128) {
    const int e = tid;
    float h = b1[e];
    const float* w1r = w1 + e * 128;
    for (int f = 0; f < 128; ++f) h += w1r[f] * s_ln[f];
    h = 0.5f * h * (1.f + erff(h * 0.70710678118654752f));
    s_hid[e] = h;
  }
  __syncthreads();
  if (tid < 2) {
    float acc = b2[tid];
    const float* w2r = w2 + tid * 128;
    for (int f = 0; f < 128; ++f) acc += w2r[f] * s_hid[f];
    out[b * 2 + tid] = acc;
  }
}

extern "C" void kernel_launch(void* const* d_in, const int* in_sizes, int n_in,
                              void* d_out, int out_size, void* d_ws, size_t ws_size,
                              hipStream_t stream) {
  const float* x       = (const float*)d_in[0];
  const float* theta_w = (const float*)d_in[1];
  const float* theta_b = (const float*)d_in[2];
  const float* ipw     = (const float*)d_in[3];
  const float* ipb     = (const float*)d_in[4];
  const float* outw    = (const float*)d_in[5];
  const float* outb    = (const float*)d_in[6];
  const float* ln_g    = (const float*)d_in[7];
  const float* ln_b    = (const float*)d_in[8];
  const float* w1      = (const float*)d_in[9];
  const float* b1      = (const float*)d_in[10];
  const float* w2      = (const float*)d_in[11];
  const float* b2      = (const float*)d_in[12];

  (void)d_ws; (void)ws_size;  // no workspace needed — everything lives in LDS

  k_fused<<<32, 1024, 0, stream>>>(x, theta_w, theta_b, ipw, ipb, outw, outb,
                                   ln_g, ln_b, w1, b1, w2, b2, (float*)d_out);
}

// Round 2
// 112.268 us; speedup vs baseline: 1.0529x; 1.0529x over previous
//
#include <hip/hip_runtime.h>
#include <math.h>

// Problem constants: B=32, T=1024, D_IN=64, H=128, NH=4, HD=32, R=3
#define TT 1024

// ---------------------------------------------------------------------------
// K1: one block per (b,n) pair. 128 blocks x 1024 threads.
// Mapping: b = bid & 31, n = bid >> 5 -> all 4 heads of a batch land on the
// same XCD (dispatch round-robin bid%8), keeping x[b] L2-local across heads.
// Phases (LDS-resident, same arithmetic order as the verified fused kernel):
//   A: xs -> y -> q[n-slice] -> z -> r[64]   (per-b part duplicated 4x, tiny)
//   B: t[j] = x[b,j,:].r  for all 1024 j     (16-lane float4+shfl dot)
//   C: smooth -> softmax -> Adj^T smooth     (1024 threads, 1 j each)
//   D: u[d] = sum_j p~[j] x[b,j,d]           (16 chunk-partials, reduce)
// Writes u to workspace: u_ws[(b*4+n)*64 + d].
// ---------------------------------------------------------------------------
__global__ __launch_bounds__(1024) void k_bn(
    const float* __restrict__ x, const float* __restrict__ theta_w,
    const float* __restrict__ theta_b, const float* __restrict__ ipw,
    const float* __restrict__ ipb, float* __restrict__ u_ws) {
  const int bid = blockIdx.x;
  const int b = bid & 31;
  const int n = bid >> 5;
  const int tid = threadIdx.x;

  __shared__ float s_xs[64];
  __shared__ float s_y[128];
  __shared__ float s_qn[32];
  __shared__ float s_z[128];
  __shared__ __align__(16) float s_r[64];
  __shared__ __align__(16) float s_t[TT];
  __shared__ __align__(16) float s_p[TT];
  __shared__ __align__(16) float s_pt[TT];
  __shared__ float s_up[16][64];
  __shared__ float s_red[16];

  const float* __restrict__ xb = x + (size_t)b * TT * 64;

  // ---------------- A ----------------
  if (tid < 64) {
    float acc = xb[(TT - 1) * 64 + tid]
              + 0.5f        * xb[(TT - 2) * 64 + tid]
              + (1.f / 3.f) * xb[(TT - 3) * 64 + tid]
              + 0.25f       * xb[(TT - 4) * 64 + tid];
    s_xs[tid] = acc * (12.f / 25.f);
  }
  __syncthreads();
  if (tid < 128) {  // y = theta*xs + theta_b (full y needed for q slice)
    const float* tr = theta_w + tid * 64;
    float acc = theta_b[tid];
    for (int d = 0; d < 64; ++d) acc += tr[d] * s_xs[d];
    s_y[tid] = acc;
  }
  __syncthreads();
  if (tid < 512) {  // q_n[g] = Wq[n*32+g,:].y + ipb[n*32+g], 16-lane dot
    const int g = tid >> 4, l = tid & 15;
    const int e = n * 32 + g;
    const float* wr = ipw + e * 128 + l * 8;
    float acc = 0.f;
    #pragma unroll
    for (int u = 0; u < 8; ++u) acc += wr[u] * s_y[l * 8 + u];
    acc += __shfl_xor(acc, 1);
    acc += __shfl_xor(acc, 2);
    acc += __shfl_xor(acc, 4);
    acc += __shfl_xor(acc, 8);
    if (l == 0) s_qn[g] = acc + ipb[e];
  }
  __syncthreads();
  if (tid < 128) {  // z[c] = sum_e Wk[128+n*32+e, c] * q_n[e]
    const int c = tid;
    float acc = 0.f;
    for (int e = 0; e < 32; ++e)
      acc += ipw[(128 + n * 32 + e) * 128 + c] * s_qn[e];
    s_z[c] = acc;
  }
  __syncthreads();
  if (tid < 64) {  // r[d] = sum_c theta[c,d] z[c], fold 1/sqrt(32)
    const int d = tid;
    float acc = 0.f;
    for (int c = 0; c < 128; ++c) acc += theta_w[c * 64 + d] * s_z[c];
    s_r[d] = acc * 0.17677669529663687f;
  }
  __syncthreads();

  // ---------------- B: t[j] = x[b,j,:].r ----------------
  {
    const int g = tid >> 4, l = tid & 15;  // 64 row-groups x 16 lanes
    const float4 rv = ((const float4*)s_r)[l];
    for (int it = 0; it < 16; ++it) {
      const int j = it * 64 + g;
      const float4 xv = ((const float4*)(xb + j * 64))[l];
      float p = xv.x * rv.x + xv.y * rv.y + xv.z * rv.z + xv.w * rv.w;
      #pragma unroll
      for (int m = 1; m <= 8; m <<= 1) p += __shfl_xor(p, m);
      if (l == 0) s_t[j] = p;
    }
  }
  __syncthreads();

  // ---------------- C: smooth, softmax, Adj^T smooth ----------------
  {
    const int j = tid;
    float acc = 0.f, wsum = 0.f;
    #pragma unroll
    for (int dj = -3; dj <= 3; ++dj) {
      const int jj = j + dj;
      if (jj >= 0 && jj < TT) {
        const float w = 1.f / (1.f + (float)(dj < 0 ? -dj : dj));
        acc += w * s_t[jj];
        wsum += w;
      }
    }
    const float sc = acc / wsum;
    float lmax = sc;
    #pragma unroll
    for (int m = 32; m >= 1; m >>= 1) lmax = fmaxf(lmax, __shfl_xor(lmax, m));
    if ((tid & 63) == 0) s_red[tid >> 6] = lmax;
    __syncthreads();
    float bmax = -1e30f;
    #pragma unroll
    for (int w = 0; w < 16; ++w) bmax = fmaxf(bmax, s_red[w]);
    __syncthreads();
    const float e = expf(sc - bmax);
    s_p[j] = e / wsum;  // pre-divide by rowsum for the Adj^T pass
    float lsum = e;
    #pragma unroll
    for (int m = 32; m >= 1; m >>= 1) lsum += __shfl_xor(lsum, m);
    if ((tid & 63) == 0) s_red[tid >> 6] = lsum;
    __syncthreads();
    float tsum = 0.f;
    #pragma unroll
    for (int w = 0; w < 16; ++w) tsum += s_red[w];
    const float inv_denom = 1.f / tsum;
    float acc2 = 0.f;
    #pragma unroll
    for (int dj = -3; dj <= 3; ++dj) {
      const int s = j + dj;
      if (s >= 0 && s < TT)
        acc2 += (1.f / (1.f + (float)(dj < 0 ? -dj : dj))) * s_p[s];
    }
    s_pt[j] = acc2 * inv_denom;
  }
  __syncthreads();

  // ---------------- D: u[d] = sum_j p~[j] x[b,j,d] ----------------
  {
    const int jp = tid >> 6, d = tid & 63;  // 16 chunks x 64 d
    const float* xr = xb + (size_t)(jp * 64) * 64 + d;
    float acc = 0.f;
    for (int jj = 0; jj < 64; ++jj)
      acc += s_pt[jp * 64 + jj] * xr[jj * 64];
    s_up[jp][d] = acc;
  }
  __syncthreads();
  if (tid < 64) {  // chunk reduce, ascending (matches verified order)
    const int d = tid;
    float acc = 0.f;
    for (int c = 0; c < 16; ++c) acc += s_up[c][d];
    u_ws[((size_t)b * 4 + n) * 64 + d] = acc;
  }
}

// ---------------------------------------------------------------------------
// K2: tail per b. 32 blocks x 128 threads. Verbatim verified epilogue,
// reading the already-reduced u from workspace.
// ---------------------------------------------------------------------------
__global__ __launch_bounds__(128) void k_tail(
    const float* __restrict__ u_in, const float* __restrict__ theta_w,
    const float* __restrict__ theta_b, const float* __restrict__ ipw,
    const float* __restrict__ ipb, const float* __restrict__ Wout,
    const float* __restrict__ outb, const float* __restrict__ ln_g,
    const float* __restrict__ ln_b, const float* __restrict__ w1,
    const float* __restrict__ b1, const float* __restrict__ w2,
    const float* __restrict__ b2, float* __restrict__ out) {
  const int b = blockIdx.x;
  const int tid = threadIdx.x;
  __shared__ float s_u[256];      // [n][d]
  __shared__ float s_w[4][128];   // theta*u + theta_b per head
  __shared__ float s_o[128], s_ln[128], s_hid[128], s_red[2];

  for (int rep = 0; rep < 2; ++rep) {
    const int idx = tid + rep * 128;
    s_u[idx] = u_in[b * 256 + idx];
  }
  __syncthreads();
  // w[n][c] = theta[c,:].u(n) + theta_b[c]
  for (int rep = 0; rep < 4; ++rep) {
    const int idx = tid + rep * 128;
    const int n = idx >> 7, c = idx & 127;
    const float* tr = theta_w + c * 64;
    const float* un = &s_u[n * 64];
    float acc = theta_b[c];
    for (int d = 0; d < 64; ++d) acc += tr[d] * un[d];
    s_w[n][c] = acc;
  }
  __syncthreads();
  // o_e = Wv[256+e,:].w(n(e)) + ipb[256+e]
  {
    const int e = tid, n = e >> 5;
    const float* wr = ipw + (256 + e) * 128;
    const float* wn = s_w[n];
    float acc = ipb[256 + e];
    for (int c = 0; c < 128; ++c) acc += wr[c] * wn[c];
    s_o[e] = acc;
  }
  __syncthreads();
  const int e = tid;
  float a = outb[e];
  {
    const float* wr = Wout + e * 128;
    for (int f = 0; f < 128; ++f) a += wr[f] * s_o[f];
  }
  float sum = a;
  #pragma unroll
  for (int m = 32; m >= 1; m >>= 1) sum += __shfl_xor(sum, m);
  if ((e & 63) == 0) s_red[e >> 6] = sum;
  __syncthreads();
  const float mu = (s_red[0] + s_red[1]) * (1.f / 128.f);
  __syncthreads();
  const float d = a - mu;
  float sq = d * d;
  #pragma unroll
  for (int m = 32; m >= 1; m >>= 1) sq += __shfl_xor(sq, m);
  if ((e & 63) == 0) s_red[e >> 6] = sq;
  __syncthreads();
  const float var = (s_red[0] + s_red[1]) * (1.f / 128.f);
  const float ln = d / sqrtf(var + 1e-5f) * ln_g[e] + ln_b[e];
  s_ln[e] = ln;
  __syncthreads();
  float h = b1[e];
  {
    const float* w1r = w1 + e * 128;
    for (int f = 0; f < 128; ++f) h += w1r[f] * s_ln[f];
  }
  h = 0.5f * h * (1.f + erff(h * 0.70710678118654752f));
  s_hid[e] = h;
  __syncthreads();
  if (e < 2) {
    float acc = b2[e];
    const float* w2r = w2 + e * 128;
    for (int f = 0; f < 128; ++f) acc += w2r[f] * s_hid[f];
    out[b * 2 + e] = acc;
  }
}

extern "C" void kernel_launch(void* const* d_in, const int* in_sizes, int n_in,
                              void* d_out, int out_size, void* d_ws, size_t ws_size,
                              hipStream_t stream) {
  const float* x       = (const float*)d_in[0];
  const float* theta_w = (const float*)d_in[1];
  const float* theta_b = (const float*)d_in[2];
  const float* ipw     = (const float*)d_in[3];
  const float* ipb     = (const float*)d_in[4];
  const float* outw    = (const float*)d_in[5];
  const float* outb    = (const float*)d_in[6];
  const float* ln_g    = (const float*)d_in[7];
  const float* ln_b    = (const float*)d_in[8];
  const float* w1      = (const float*)d_in[9];
  const float* b1      = (const float*)d_in[10];
  const float* w2      = (const float*)d_in[11];
  const float* b2      = (const float*)d_in[12];

  float* u_ws = (float*)d_ws;  // 32*4*64 = 8192 floats

  k_bn  <<<128, 1024, 0, stream>>>(x, theta_w, theta_b, ipw, ipb, u_ws);
  k_tail<<< 32,  128, 0, stream>>>(u_ws, theta_w, theta_b, ipw, ipb, outw, outb,
                                   ln_g, ln_b, w1, b1, w2, b2, (float*)d_out);
}

// Round 3
// 109.232 us; speedup vs baseline: 1.0822x; 1.0278x over previous
//
#include <hip/hip_runtime.h>
#include <math.h>

// Problem constants: B=32, T=1024, D_IN=64, H=128, NH=4, HD=32, R=3
#define TT 1024

// ---------------------------------------------------------------------------
// K1: one block per (b,n) pair. 128 blocks x 1024 threads.
// b = bid & 31, n = bid >> 5 (4 heads of a batch share an XCD -> x[b] L2-local)
// Latency-hiding restructure vs round 2:
//  - Phase-B x fragments preloaded to registers BEFORE phase A (no dependency)
//  - Phase-A r-matvec spread over 512 threads with unrolled 16-wide partials
//  - Full unrolls on all load loops (bulk-issue, one waitcnt per batch)
// ---------------------------------------------------------------------------
__global__ __launch_bounds__(1024) void k_bn(
    const float* __restrict__ x, const float* __restrict__ theta_w,
    const float* __restrict__ theta_b, const float* __restrict__ ipw,
    const float* __restrict__ ipb, float* __restrict__ u_ws) {
  const int bid = blockIdx.x;
  const int b = bid & 31;
  const int n = bid >> 5;
  const int tid = threadIdx.x;

  __shared__ float s_xs[64];
  __shared__ float s_y[128];
  __shared__ float s_qn[32];
  __shared__ float s_z[128];
  __shared__ float s_rp[8][64];
  __shared__ __align__(16) float s_r[64];
  __shared__ __align__(16) float s_t[TT];
  __shared__ __align__(16) float s_p[TT];
  __shared__ __align__(16) float s_pt[TT];
  __shared__ float s_up[16][64];
  __shared__ float s_red[16];

  const float* __restrict__ xb = x + (size_t)b * TT * 64;

  // ---- Phase-B preload: 16 float4 x-fragments per thread, issued up front
  // so their latency hides under the whole of phase A.
  const int g = tid >> 4, l = tid & 15;  // 64 row-groups x 16 lanes
  float4 xv[16];
  #pragma unroll
  for (int it = 0; it < 16; ++it)
    xv[it] = ((const float4*)(xb + (size_t)(it * 64 + g) * 64))[l];

  // ---------------- A ----------------
  if (tid < 64) {
    float acc = xb[(TT - 1) * 64 + tid]
              + 0.5f        * xb[(TT - 2) * 64 + tid]
              + (1.f / 3.f) * xb[(TT - 3) * 64 + tid]
              + 0.25f       * xb[(TT - 4) * 64 + tid];
    s_xs[tid] = acc * (12.f / 25.f);
  }
  __syncthreads();
  if (tid < 128) {  // y = theta*xs + theta_b
    const float* tr = theta_w + tid * 64;
    float acc = theta_b[tid];
    #pragma unroll 16
    for (int d = 0; d < 64; ++d) acc += tr[d] * s_xs[d];
    s_y[tid] = acc;
  }
  __syncthreads();
  if (tid < 512) {  // q_n[gq] = Wq[n*32+gq,:].y + ipb, 16-lane dot
    const int gq = tid >> 4, lq = tid & 15;
    const int e = n * 32 + gq;
    const float* wr = ipw + e * 128 + lq * 8;
    float acc = 0.f;
    #pragma unroll
    for (int u = 0; u < 8; ++u) acc += wr[u] * s_y[lq * 8 + u];
    acc += __shfl_xor(acc, 1);
    acc += __shfl_xor(acc, 2);
    acc += __shfl_xor(acc, 4);
    acc += __shfl_xor(acc, 8);
    if (lq == 0) s_qn[gq] = acc + ipb[e];
  }
  __syncthreads();
  if (tid < 128) {  // z[c] = sum_e Wk[128+n*32+e, c] * q_n[e], bulk-issued
    const int c = tid;
    float acc = 0.f;
    #pragma unroll
    for (int e = 0; e < 32; ++e)
      acc += ipw[(128 + n * 32 + e) * 128 + c] * s_qn[e];
    s_z[c] = acc;
  }
  __syncthreads();
  if (tid < 512) {  // r partials: group gr owns c in [gr*16, gr*16+16)
    const int gr = tid >> 6, d = tid & 63;
    float acc = 0.f;
    #pragma unroll
    for (int cc = 0; cc < 16; ++cc) {
      const int c = gr * 16 + cc;
      acc += theta_w[c * 64 + d] * s_z[c];
    }
    s_rp[gr][d] = acc;
  }
  __syncthreads();
  if (tid < 64) {  // reduce 8 partials, fold 1/sqrt(32)
    float acc = 0.f;
    #pragma unroll
    for (int gr = 0; gr < 8; ++gr) acc += s_rp[gr][tid];
    s_r[tid] = acc * 0.17677669529663687f;
  }
  __syncthreads();

  // ---------------- B: t[j] = x[b,j,:].r (x already in registers) --------
  {
    const float4 rv = ((const float4*)s_r)[l];
    #pragma unroll
    for (int it = 0; it < 16; ++it) {
      const int j = it * 64 + g;
      const float4 xv4 = xv[it];
      float p = xv4.x * rv.x + xv4.y * rv.y + xv4.z * rv.z + xv4.w * rv.w;
      #pragma unroll
      for (int m = 1; m <= 8; m <<= 1) p += __shfl_xor(p, m);
      if (l == 0) s_t[j] = p;
    }
  }
  __syncthreads();

  // ---------------- C: smooth, softmax, Adj^T smooth ----------------
  {
    const int j = tid;
    float acc = 0.f, wsum = 0.f;
    #pragma unroll
    for (int dj = -3; dj <= 3; ++dj) {
      const int jj = j + dj;
      if (jj >= 0 && jj < TT) {
        const float w = 1.f / (1.f + (float)(dj < 0 ? -dj : dj));
        acc += w * s_t[jj];
        wsum += w;
      }
    }
    const float sc = acc / wsum;
    float lmax = sc;
    #pragma unroll
    for (int m = 32; m >= 1; m >>= 1) lmax = fmaxf(lmax, __shfl_xor(lmax, m));
    if ((tid & 63) == 0) s_red[tid >> 6] = lmax;
    __syncthreads();
    float bmax = -1e30f;
    #pragma unroll
    for (int w = 0; w < 16; ++w) bmax = fmaxf(bmax, s_red[w]);
    __syncthreads();
    const float e = expf(sc - bmax);
    s_p[j] = e / wsum;  // pre-divide by rowsum for the Adj^T pass
    float lsum = e;
    #pragma unroll
    for (int m = 32; m >= 1; m >>= 1) lsum += __shfl_xor(lsum, m);
    if ((tid & 63) == 0) s_red[tid >> 6] = lsum;
    __syncthreads();
    float tsum = 0.f;
    #pragma unroll
    for (int w = 0; w < 16; ++w) tsum += s_red[w];
    const float inv_denom = 1.f / tsum;
    float acc2 = 0.f;
    #pragma unroll
    for (int dj = -3; dj <= 3; ++dj) {
      const int s = j + dj;
      if (s >= 0 && s < TT)
        acc2 += (1.f / (1.f + (float)(dj < 0 ? -dj : dj))) * s_p[s];
    }
    s_pt[j] = acc2 * inv_denom;
  }
  __syncthreads();

  // ---------------- D: u[d] = sum_j p~[j] x[b,j,d], bulk-issued ----------
  {
    const int jp = tid >> 6, d = tid & 63;  // 16 chunks x 64 d
    const float* xr = xb + (size_t)(jp * 64) * 64 + d;
    float acc = 0.f;
    #pragma unroll
    for (int jj = 0; jj < 64; ++jj)
      acc += s_pt[jp * 64 + jj] * xr[jj * 64];
    s_up[jp][d] = acc;
  }
  __syncthreads();
  if (tid < 64) {  // chunk reduce, ascending
    const int d = tid;
    float acc = 0.f;
    #pragma unroll
    for (int c = 0; c < 16; ++c) acc += s_up[c][d];
    u_ws[((size_t)b * 4 + n) * 64 + d] = acc;
  }
}

// ---------------------------------------------------------------------------
// K2: tail per b. 32 blocks x 128 threads. Verified epilogue + bulk-issue
// unrolls on the inner mat-vec loops.
// ---------------------------------------------------------------------------
__global__ __launch_bounds__(128) void k_tail(
    const float* __restrict__ u_in, const float* __restrict__ theta_w,
    const float* __restrict__ theta_b, const float* __restrict__ ipw,
    const float* __restrict__ ipb, const float* __restrict__ Wout,
    const float* __restrict__ outb, const float* __restrict__ ln_g,
    const float* __restrict__ ln_b, const float* __restrict__ w1,
    const float* __restrict__ b1, const float* __restrict__ w2,
    const float* __restrict__ b2, float* __restrict__ out) {
  const int b = blockIdx.x;
  const int tid = threadIdx.x;
  __shared__ float s_u[256];      // [n][d]
  __shared__ float s_w[4][128];   // theta*u + theta_b per head
  __shared__ float s_o[128], s_ln[128], s_hid[128], s_red[2];

  #pragma unroll
  for (int rep = 0; rep < 2; ++rep) {
    const int idx = tid + rep * 128;
    s_u[idx] = u_in[b * 256 + idx];
  }
  __syncthreads();
  // w[n][c] = theta[c,:].u(n) + theta_b[c]
  #pragma unroll
  for (int rep = 0; rep < 4; ++rep) {
    const int idx = tid + rep * 128;
    const int n = idx >> 7, c = idx & 127;
    const float* tr = theta_w + c * 64;
    const float* un = &s_u[n * 64];
    float acc = theta_b[c];
    #pragma unroll 16
    for (int d = 0; d < 64; ++d) acc += tr[d] * un[d];
    s_w[n][c] = acc;
  }
  __syncthreads();
  // o_e = Wv[256+e,:].w(n(e)) + ipb[256+e]
  {
    const int e = tid, n = e >> 5;
    const float* wr = ipw + (256 + e) * 128;
    const float* wn = s_w[n];
    float acc = ipb[256 + e];
    #pragma unroll 16
    for (int c = 0; c < 128; ++c) acc += wr[c] * wn[c];
    s_o[e] = acc;
  }
  __syncthreads();
  const int e = tid;
  float a = outb[e];
  {
    const float* wr = Wout + e * 128;
    #pragma unroll 16
    for (int f = 0; f < 128; ++f) a += wr[f] * s_o[f];
  }
  float sum = a;
  #pragma unroll
  for (int m = 32; m >= 1; m >>= 1) sum += __shfl_xor(sum, m);
  if ((e & 63) == 0) s_red[e >> 6] = sum;
  __syncthreads();
  const float mu = (s_red[0] + s_red[1]) * (1.f / 128.f);
  __syncthreads();
  const float d = a - mu;
  float sq = d * d;
  #pragma unroll
  for (int m = 32; m >= 1; m >>= 1) sq += __shfl_xor(sq, m);
  if ((e & 63) == 0) s_red[e >> 6] = sq;
  __syncthreads();
  const float var = (s_red[0] + s_red[1]) * (1.f / 128.f);
  const float ln = d / sqrtf(var + 1e-5f) * ln_g[e] + ln_b[e];
  s_ln[e] = ln;
  __syncthreads();
  float h = b1[e];
  {
    const float* w1r = w1 + e * 128;
    #pragma unroll 16
    for (int f = 0; f < 128; ++f) h += w1r[f] * s_ln[f];
  }
  h = 0.5f * h * (1.f + erff(h * 0.70710678118654752f));
  s_hid[e] = h;
  __syncthreads();
  if (e < 2) {
    float acc = b2[e];
    const float* w2r = w2 + e * 128;
    #pragma unroll 16
    for (int f = 0; f < 128; ++f) acc += w2r[f] * s_hid[f];
    out[b * 2 + e] = acc;
  }
}

extern "C" void kernel_launch(void* const* d_in, const int* in_sizes, int n_in,
                              void* d_out, int out_size, void* d_ws, size_t ws_size,
                              hipStream_t stream) {
  const float* x       = (const float*)d_in[0];
  const float* theta_w = (const float*)d_in[1];
  const float* theta_b = (const float*)d_in[2];
  const float* ipw     = (const float*)d_in[3];
  const float* ipb     = (const float*)d_in[4];
  const float* outw    = (const float*)d_in[5];
  const float* outb    = (const float*)d_in[6];
  const float* ln_g    = (const float*)d_in[7];
  const float* ln_b    = (const float*)d_in[8];
  const float* w1      = (const float*)d_in[9];
  const float* b1      = (const float*)d_in[10];
  const float* w2      = (const float*)d_in[11];
  const float* b2      = (const float*)d_in[12];

  float* u_ws = (float*)d_ws;  // 32*4*64 = 8192 floats

  k_bn  <<<128, 1024, 0, stream>>>(x, theta_w, theta_b, ipw, ipb, u_ws);
  k_tail<<< 32,  128, 0, stream>>>(u_ws, theta_w, theta_b, ipw, ipb, outw, outb,
                                   ln_g, ln_b, w1, b1, w2, b2, (float*)d_out);
}